// Round 13
// baseline (49.931 us; speedup 1.0000x reference)
//
#include <hip/hip_runtime.h>
#include <hip/hip_bf16.h>

#define L_SEQ 1024
#define NT 32          // total 32-row KV tiles
#define NT_H 16        // tiles per KV half

typedef __attribute__((ext_vector_type(8))) __bf16 bf16x8;
typedef __attribute__((ext_vector_type(4))) __bf16 bf16x4;
typedef __attribute__((ext_vector_type(4))) float f32x4;

__device__ __forceinline__ float fast_exp2(float x) {
#if __has_builtin(__builtin_amdgcn_exp2f)
    return __builtin_amdgcn_exp2f(x);
#else
    return exp2f(x);
#endif
}

#define MFMA16(a, b, c) __builtin_amdgcn_mfma_f32_16x16x32_bf16((a), (b), (c), 0, 0, 0)

// ===========================================================================
// Phase A: KV-split partial attention. 1024 blocks = 512 (batch,q-tile) x 2
// KV halves; each block runs the R12 fused body for 16 tiles and writes
// UNNORMALIZED partial O (f32) + per-row partial l. Half 0 -> O0 (=d_out),
// half 1 -> O1 (=d_ws). Partials combine exactly: O = (O0+O1)/(l0+l1).
// ===========================================================================
__global__ __launch_bounds__(256) void sdpa_partial(
    const float* __restrict__ Q, const float* __restrict__ K,
    const float* __restrict__ V, float* __restrict__ O0,
    float* __restrict__ O1, float* __restrict__ L0, float* __restrict__ L1)
{
    __shared__ __align__(16) char lds[2 * 8192];

    const int tid  = threadIdx.x;
    const int lane = tid & 63;
    const int wave = tid >> 6;
    const int li   = lane & 15;
    const int h    = lane >> 4;

    // XCD-chunked swizzle over 1024 blocks; decode (batch, q-tile, half).
    const int wg = blockIdx.x;
    const int lb = (wg & 7) * 128 + (wg >> 3);
    const int b    = lb >> 4;
    const int rest = lb & 15;
    const int qt   = rest >> 1;      // 0..7 (128-row q-tile)
    const int half = rest & 1;       // KV half
    const int q0 = qt * 128 + wave * 16 + li;   // q-block B rows are q0 + 64

    const float* Qb = Q + (size_t)b * L_SEQ * 64;
    const char*  Kb = (const char*)(K + (size_t)b * L_SEQ * 64);
    const char*  Vb = (const char*)(V + (size_t)b * L_SEQ * 64);

    // ---- staging dest offsets (tile-invariant, R12 layout)
    int kd0, kd1, vd0, vd1;
    {
        int kd[2], vd[2];
        #pragma unroll
        for (int i = 0; i < 2; ++i) {
            const int qi = tid + i * 256;
            const int r  = qi >> 4;
            const int d4 = (qi & 15) << 2;
            const int c32 = d4 >> 5, rem = d4 & 31, hf = rem >> 4, hh = (rem & 15) >> 2;
            kd[i] = r * 128 + 2 * (((c32 * 32 + hh * 8) ^ ((r & 7) * 8)) + hf * 4);
            const int vhf = r >> 4, vh = (r & 15) >> 2, vj = r & 3;
            const int col = (vh ^ ((d4 >> 2) & 3)) * 8 + vhf * 4 + vj;
            vd[i] = 4096 + d4 * 64 + 2 * col;
        }
        kd0 = kd[0]; kd1 = kd[1]; vd0 = vd[0]; vd1 = vd[1];
    }

    // ---- Q fragments (both q-blocks): fold (1/temperature)*log2(e)
    const float QSC = 0.18033688011112042f;   // 0.125 * log2(e)
    bf16x8 qA0, qA1, qB0, qB1;
    {
        const float* ra = &Qb[(size_t)q0 * 64];
        const float* rb = &Qb[(size_t)(q0 + 64) * 64];
        f32x4 a00 = *(const f32x4*)&ra[0  + h * 4];
        f32x4 a01 = *(const f32x4*)&ra[16 + h * 4];
        f32x4 a10 = *(const f32x4*)&ra[32 + h * 4];
        f32x4 a11 = *(const f32x4*)&ra[48 + h * 4];
        f32x4 b00 = *(const f32x4*)&rb[0  + h * 4];
        f32x4 b01 = *(const f32x4*)&rb[16 + h * 4];
        f32x4 b10 = *(const f32x4*)&rb[32 + h * 4];
        f32x4 b11 = *(const f32x4*)&rb[48 + h * 4];
        #pragma unroll
        for (int j = 0; j < 4; ++j) {
            qA0[j]     = (__bf16)(a00[j] * QSC);
            qA0[4 + j] = (__bf16)(a01[j] * QSC);
            qA1[j]     = (__bf16)(a10[j] * QSC);
            qA1[4 + j] = (__bf16)(a11[j] * QSC);
            qB0[j]     = (__bf16)(b00[j] * QSC);
            qB0[4 + j] = (__bf16)(b01[j] * QSC);
            qB1[j]     = (__bf16)(b10[j] * QSC);
            qB1[4 + j] = (__bf16)(b11[j] * QSC);
        }
    }

    bf16x8 ones;
    #pragma unroll
    for (int j = 0; j < 8; ++j) ones[j] = (__bf16)1.0f;

    const float NBIAS = -46.0f;
    f32x4 oA0 = {0.f,0.f,0.f,0.f}, oA1 = {0.f,0.f,0.f,0.f};
    f32x4 oA2 = {0.f,0.f,0.f,0.f}, oA3 = {0.f,0.f,0.f,0.f};
    f32x4 oB0 = {0.f,0.f,0.f,0.f}, oB1 = {0.f,0.f,0.f,0.f};
    f32x4 oB2 = {0.f,0.f,0.f,0.f}, oB3 = {0.f,0.f,0.f,0.f};
    f32x4 olA = {0.f,0.f,0.f,0.f}, olB = {0.f,0.f,0.f,0.f};

    // ---- reg-staging (tile index is absolute: half*NT_H + t)
    f32x4 sk0, sk1, sv0, sv1;
    auto load = [&](int t) {
        const size_t tb = (size_t)(half * NT_H + t) * 8192;
        sk0 = *(const f32x4*)(Kb + tb + (tid << 4));
        sk1 = *(const f32x4*)(Kb + tb + ((tid + 256) << 4));
        sv0 = *(const f32x4*)(Vb + tb + (tid << 4));
        sv1 = *(const f32x4*)(Vb + tb + ((tid + 256) << 4));
    };
    auto writebuf = [&](int bi) {
        char* B = lds + bi * 8192;
        bf16x4 a, c;
        #pragma unroll
        for (int j = 0; j < 4; ++j) { a[j] = (__bf16)sk0[j]; c[j] = (__bf16)sk1[j]; }
        *(bf16x4*)(B + kd0) = a;
        *(bf16x4*)(B + kd1) = c;
        #pragma unroll
        for (int u = 0; u < 4; ++u) {
            *((__bf16*)(B + vd0 + 64 * u)) = (__bf16)sv0[u];
            *((__bf16*)(B + vd1 + 64 * u)) = (__bf16)sv1[u];
        }
    };

    const int kswz = (li & 7) << 4;
    const int vswz = ((li >> 2) & 3) << 4;

    auto body = [&](int bi) {
        const char* bb = lds + bi * 8192;
        bf16x8 kf00 = *(const bf16x8*)(bb + li * 128 + ((h * 16) ^ kswz));
        bf16x8 kf01 = *(const bf16x8*)(bb + li * 128 + ((64 + h * 16) ^ kswz));
        bf16x8 kf10 = *(const bf16x8*)(bb + 2048 + li * 128 + ((h * 16) ^ kswz));
        bf16x8 kf11 = *(const bf16x8*)(bb + 2048 + li * 128 + ((64 + h * 16) ^ kswz));
        const char* vb = bb + 4096;
        bf16x8 vf0 = *(const bf16x8*)(vb + (0 * 16 + li) * 64 + ((h * 16) ^ vswz));
        bf16x8 vf1 = *(const bf16x8*)(vb + (1 * 16 + li) * 64 + ((h * 16) ^ vswz));
        bf16x8 vf2 = *(const bf16x8*)(vb + (2 * 16 + li) * 64 + ((h * 16) ^ vswz));
        bf16x8 vf3 = *(const bf16x8*)(vb + (3 * 16 + li) * 64 + ((h * 16) ^ vswz));
        asm volatile("s_waitcnt lgkmcnt(0)" ::: "memory");

        const f32x4 nb = {NBIAS, NBIAS, NBIAS, NBIAS};
        __builtin_amdgcn_s_setprio(1);
        f32x4 sA0 = MFMA16(kf01, qA1, MFMA16(kf00, qA0, nb));
        f32x4 sA1 = MFMA16(kf11, qA1, MFMA16(kf10, qA0, nb));
        f32x4 sB0 = MFMA16(kf01, qB1, MFMA16(kf00, qB0, nb));
        f32x4 sB1 = MFMA16(kf11, qB1, MFMA16(kf10, qB0, nb));
        __builtin_amdgcn_s_setprio(0);

        bf16x8 pfA, pfB;
        #pragma unroll
        for (int r = 0; r < 4; ++r) {
            pfA[r]     = (__bf16)fast_exp2(sA0[r]);
            pfA[4 + r] = (__bf16)fast_exp2(sA1[r]);
            pfB[r]     = (__bf16)fast_exp2(sB0[r]);
            pfB[4 + r] = (__bf16)fast_exp2(sB1[r]);
        }

        __builtin_amdgcn_s_setprio(1);
        oA0 = MFMA16(vf0, pfA, oA0);
        oA1 = MFMA16(vf1, pfA, oA1);
        oA2 = MFMA16(vf2, pfA, oA2);
        oA3 = MFMA16(vf3, pfA, oA3);
        olA = MFMA16(ones, pfA, olA);
        oB0 = MFMA16(vf0, pfB, oB0);
        oB1 = MFMA16(vf1, pfB, oB1);
        oB2 = MFMA16(vf2, pfB, oB2);
        oB3 = MFMA16(vf3, pfB, oB3);
        olB = MFMA16(ones, pfB, olB);
        __builtin_amdgcn_s_setprio(0);
    };

    // ---- prologue
    load(0);
    asm volatile("s_waitcnt vmcnt(0)" ::: "memory");
    writebuf(0);
    load(1);
    asm volatile("s_waitcnt lgkmcnt(0)" ::: "memory");
    __builtin_amdgcn_s_barrier();

    #pragma unroll 2
    for (int t = 0; t < NT_H - 2; ++t) {
        asm volatile("s_waitcnt vmcnt(0)" ::: "memory");
        writebuf((t + 1) & 1);
        load(t + 2);
        body(t & 1);
        __builtin_amdgcn_s_barrier();
    }
    asm volatile("s_waitcnt vmcnt(0)" ::: "memory");
    writebuf((NT_H - 1) & 1);
    body((NT_H - 2) & 1);
    __builtin_amdgcn_s_barrier();
    body((NT_H - 1) & 1);

    // ---- epilogue: UNNORMALIZED partial O + per-row l
    float* Op = half ? O1 : O0;
    float* Lp = half ? L1 : L0;
    float* ObA = Op + ((size_t)b * L_SEQ + q0) * 64;
    float* ObB = ObA + 64 * 64;
    *(f32x4*)&ObA[0 * 16 + h * 4] = oA0;
    *(f32x4*)&ObA[1 * 16 + h * 4] = oA1;
    *(f32x4*)&ObA[2 * 16 + h * 4] = oA2;
    *(f32x4*)&ObA[3 * 16 + h * 4] = oA3;
    *(f32x4*)&ObB[0 * 16 + h * 4] = oB0;
    *(f32x4*)&ObB[1 * 16 + h * 4] = oB1;
    *(f32x4*)&ObB[2 * 16 + h * 4] = oB2;
    *(f32x4*)&ObB[3 * 16 + h * 4] = oB3;
    if (h == 0) {
        Lp[(size_t)b * L_SEQ + q0]      = olA[0];
        Lp[(size_t)b * L_SEQ + q0 + 64] = olB[0];
    }
}

// ===========================================================================
// Phase B: streaming combine O = (O0 + O1) / (l0 + l1). O0 lives in d_out
// (read-modify-write, each thread owns its elements).
// ===========================================================================
__global__ __launch_bounds__(256) void sdpa_combine(
    const float* __restrict__ O1, const float* __restrict__ L0,
    const float* __restrict__ L1, float* __restrict__ O)
{
    const int i   = blockIdx.x * 256 + threadIdx.x;   // f32x4 index
    const int row = i >> 4;
    const float l = L0[row] + L1[row];
    f32x4 a = *(const f32x4*)(O  + (size_t)i * 4);
    f32x4 c = *(const f32x4*)(O1 + (size_t)i * 4);
    const float il = 1.f / l;
    f32x4 o;
    #pragma unroll
    for (int r = 0; r < 4; ++r) o[r] = (a[r] + c[r]) * il;
    *(f32x4*)(O + (size_t)i * 4) = o;
}

// ===========================================================================
// Fallback: R12 fused single kernel (no workspace needed).
// ===========================================================================
__global__ __launch_bounds__(256) void sdpa_fused(
    const float* __restrict__ Q, const float* __restrict__ K,
    const float* __restrict__ V, float* __restrict__ O)
{
    __shared__ __align__(16) char lds[2 * 8192];

    const int tid  = threadIdx.x;
    const int lane = tid & 63;
    const int wave = tid >> 6;
    const int li   = lane & 15;
    const int h    = lane >> 4;

    const int wg = blockIdx.x;
    const int lb = (wg & 7) * 64 + (wg >> 3);
    const int b  = lb >> 3;
    const int qt = lb & 7;
    const int q0 = qt * 128 + wave * 16 + li;

    const float* Qb = Q + (size_t)b * L_SEQ * 64;
    const char*  Kb = (const char*)(K + (size_t)b * L_SEQ * 64);
    const char*  Vb = (const char*)(V + (size_t)b * L_SEQ * 64);

    int kd0, kd1, vd0, vd1;
    {
        int kd[2], vd[2];
        #pragma unroll
        for (int i = 0; i < 2; ++i) {
            const int qi = tid + i * 256;
            const int r  = qi >> 4;
            const int d4 = (qi & 15) << 2;
            const int c32 = d4 >> 5, rem = d4 & 31, hf = rem >> 4, hh = (rem & 15) >> 2;
            kd[i] = r * 128 + 2 * (((c32 * 32 + hh * 8) ^ ((r & 7) * 8)) + hf * 4);
            const int vhf = r >> 4, vh = (r & 15) >> 2, vj = r & 3;
            const int col = (vh ^ ((d4 >> 2) & 3)) * 8 + vhf * 4 + vj;
            vd[i] = 4096 + d4 * 64 + 2 * col;
        }
        kd0 = kd[0]; kd1 = kd[1]; vd0 = vd[0]; vd1 = vd[1];
    }

    const float QSC = 0.18033688011112042f;
    bf16x8 qA0, qA1, qB0, qB1;
    {
        const float* ra = &Qb[(size_t)q0 * 64];
        const float* rb = &Qb[(size_t)(q0 + 64) * 64];
        f32x4 a00 = *(const f32x4*)&ra[0  + h * 4];
        f32x4 a01 = *(const f32x4*)&ra[16 + h * 4];
        f32x4 a10 = *(const f32x4*)&ra[32 + h * 4];
        f32x4 a11 = *(const f32x4*)&ra[48 + h * 4];
        f32x4 b00 = *(const f32x4*)&rb[0  + h * 4];
        f32x4 b01 = *(const f32x4*)&rb[16 + h * 4];
        f32x4 b10 = *(const f32x4*)&rb[32 + h * 4];
        f32x4 b11 = *(const f32x4*)&rb[48 + h * 4];
        #pragma unroll
        for (int j = 0; j < 4; ++j) {
            qA0[j]     = (__bf16)(a00[j] * QSC);
            qA0[4 + j] = (__bf16)(a01[j] * QSC);
            qA1[j]     = (__bf16)(a10[j] * QSC);
            qA1[4 + j] = (__bf16)(a11[j] * QSC);
            qB0[j]     = (__bf16)(b00[j] * QSC);
            qB0[4 + j] = (__bf16)(b01[j] * QSC);
            qB1[j]     = (__bf16)(b10[j] * QSC);
            qB1[4 + j] = (__bf16)(b11[j] * QSC);
        }
    }

    bf16x8 ones;
    #pragma unroll
    for (int j = 0; j < 8; ++j) ones[j] = (__bf16)1.0f;

    const float NBIAS = -46.0f;
    f32x4 oA0 = {0.f,0.f,0.f,0.f}, oA1 = {0.f,0.f,0.f,0.f};
    f32x4 oA2 = {0.f,0.f,0.f,0.f}, oA3 = {0.f,0.f,0.f,0.f};
    f32x4 oB0 = {0.f,0.f,0.f,0.f}, oB1 = {0.f,0.f,0.f,0.f};
    f32x4 oB2 = {0.f,0.f,0.f,0.f}, oB3 = {0.f,0.f,0.f,0.f};
    f32x4 olA = {0.f,0.f,0.f,0.f}, olB = {0.f,0.f,0.f,0.f};

    f32x4 sk0, sk1, sv0, sv1;
    auto load = [&](int t) {
        const size_t tb = (size_t)t * 8192;
        sk0 = *(const f32x4*)(Kb + tb + (tid << 4));
        sk1 = *(const f32x4*)(Kb + tb + ((tid + 256) << 4));
        sv0 = *(const f32x4*)(Vb + tb + (tid << 4));
        sv1 = *(const f32x4*)(Vb + tb + ((tid + 256) << 4));
    };
    auto writebuf = [&](int bi) {
        char* B = lds + bi * 8192;
        bf16x4 a, c;
        #pragma unroll
        for (int j = 0; j < 4; ++j) { a[j] = (__bf16)sk0[j]; c[j] = (__bf16)sk1[j]; }
        *(bf16x4*)(B + kd0) = a;
        *(bf16x4*)(B + kd1) = c;
        #pragma unroll
        for (int u = 0; u < 4; ++u) {
            *((__bf16*)(B + vd0 + 64 * u)) = (__bf16)sv0[u];
            *((__bf16*)(B + vd1 + 64 * u)) = (__bf16)sv1[u];
        }
    };

    const int kswz = (li & 7) << 4;
    const int vswz = ((li >> 2) & 3) << 4;

    auto body = [&](int bi) {
        const char* bb = lds + bi * 8192;
        bf16x8 kf00 = *(const bf16x8*)(bb + li * 128 + ((h * 16) ^ kswz));
        bf16x8 kf01 = *(const bf16x8*)(bb + li * 128 + ((64 + h * 16) ^ kswz));
        bf16x8 kf10 = *(const bf16x8*)(bb + 2048 + li * 128 + ((h * 16) ^ kswz));
        bf16x8 kf11 = *(const bf16x8*)(bb + 2048 + li * 128 + ((64 + h * 16) ^ kswz));
        const char* vb = bb + 4096;
        bf16x8 vf0 = *(const bf16x8*)(vb + (0 * 16 + li) * 64 + ((h * 16) ^ vswz));
        bf16x8 vf1 = *(const bf16x8*)(vb + (1 * 16 + li) * 64 + ((h * 16) ^ vswz));
        bf16x8 vf2 = *(const bf16x8*)(vb + (2 * 16 + li) * 64 + ((h * 16) ^ vswz));
        bf16x8 vf3 = *(const bf16x8*)(vb + (3 * 16 + li) * 64 + ((h * 16) ^ vswz));
        asm volatile("s_waitcnt lgkmcnt(0)" ::: "memory");

        const f32x4 nb = {NBIAS, NBIAS, NBIAS, NBIAS};
        __builtin_amdgcn_s_setprio(1);
        f32x4 sA0 = MFMA16(kf01, qA1, MFMA16(kf00, qA0, nb));
        f32x4 sA1 = MFMA16(kf11, qA1, MFMA16(kf10, qA0, nb));
        f32x4 sB0 = MFMA16(kf01, qB1, MFMA16(kf00, qB0, nb));
        f32x4 sB1 = MFMA16(kf11, qB1, MFMA16(kf10, qB0, nb));
        __builtin_amdgcn_s_setprio(0);

        bf16x8 pfA, pfB;
        #pragma unroll
        for (int r = 0; r < 4; ++r) {
            pfA[r]     = (__bf16)fast_exp2(sA0[r]);
            pfA[4 + r] = (__bf16)fast_exp2(sA1[r]);
            pfB[r]     = (__bf16)fast_exp2(sB0[r]);
            pfB[4 + r] = (__bf16)fast_exp2(sB1[r]);
        }

        __builtin_amdgcn_s_setprio(1);
        oA0 = MFMA16(vf0, pfA, oA0);
        oA1 = MFMA16(vf1, pfA, oA1);
        oA2 = MFMA16(vf2, pfA, oA2);
        oA3 = MFMA16(vf3, pfA, oA3);
        olA = MFMA16(ones, pfA, olA);
        oB0 = MFMA16(vf0, pfB, oB0);
        oB1 = MFMA16(vf1, pfB, oB1);
        oB2 = MFMA16(vf2, pfB, oB2);
        oB3 = MFMA16(vf3, pfB, oB3);
        olB = MFMA16(ones, pfB, olB);
        __builtin_amdgcn_s_setprio(0);
    };

    load(0);
    asm volatile("s_waitcnt vmcnt(0)" ::: "memory");
    writebuf(0);
    load(1);
    asm volatile("s_waitcnt lgkmcnt(0)" ::: "memory");
    __builtin_amdgcn_s_barrier();

    #pragma unroll 2
    for (int t = 0; t < NT - 2; ++t) {
        asm volatile("s_waitcnt vmcnt(0)" ::: "memory");
        writebuf((t + 1) & 1);
        load(t + 2);
        body(t & 1);
        __builtin_amdgcn_s_barrier();
    }
    asm volatile("s_waitcnt vmcnt(0)" ::: "memory");
    writebuf(31 & 1);
    body(30 & 1);
    __builtin_amdgcn_s_barrier();
    body(31 & 1);

    const float ilA = 1.f / olA[0];
    const float ilB = 1.f / olB[0];
    float* ObA = O + ((size_t)b * L_SEQ + q0) * 64;
    float* ObB = ObA + 64 * 64;
    f32x4 ov;
    #pragma unroll
    for (int r = 0; r < 4; ++r) ov[r] = oA0[r] * ilA;
    *(f32x4*)&ObA[0 * 16 + h * 4] = ov;
    #pragma unroll
    for (int r = 0; r < 4; ++r) ov[r] = oA1[r] * ilA;
    *(f32x4*)&ObA[1 * 16 + h * 4] = ov;
    #pragma unroll
    for (int r = 0; r < 4; ++r) ov[r] = oA2[r] * ilA;
    *(f32x4*)&ObA[2 * 16 + h * 4] = ov;
    #pragma unroll
    for (int r = 0; r < 4; ++r) ov[r] = oA3[r] * ilA;
    *(f32x4*)&ObA[3 * 16 + h * 4] = ov;
    #pragma unroll
    for (int r = 0; r < 4; ++r) ov[r] = oB0[r] * ilB;
    *(f32x4*)&ObB[0 * 16 + h * 4] = ov;
    #pragma unroll
    for (int r = 0; r < 4; ++r) ov[r] = oB1[r] * ilB;
    *(f32x4*)&ObB[1 * 16 + h * 4] = ov;
    #pragma unroll
    for (int r = 0; r < 4; ++r) ov[r] = oB2[r] * ilB;
    *(f32x4*)&ObB[2 * 16 + h * 4] = ov;
    #pragma unroll
    for (int r = 0; r < 4; ++r) ov[r] = oB3[r] * ilB;
    *(f32x4*)&ObB[3 * 16 + h * 4] = ov;
}

extern "C" void kernel_launch(void* const* d_in, const int* in_sizes, int n_in,
                              void* d_out, int out_size, void* d_ws, size_t ws_size,
                              hipStream_t stream) {
    const float* q = (const float*)d_in[0];
    const float* k = (const float*)d_in[1];
    const float* v = (const float*)d_in[2];
    float* o = (float*)d_out;

    const size_t OSZ = (size_t)64 * L_SEQ * 64 * sizeof(float);   // 16.78 MB
    const size_t LSZ = (size_t)64 * L_SEQ * sizeof(float);        // 256 KB
    if (ws_size >= OSZ + 2 * LSZ) {
        float* O1 = (float*)d_ws;
        float* L0 = (float*)((char*)d_ws + OSZ);
        float* L1 = (float*)((char*)d_ws + OSZ + LSZ);
        sdpa_partial<<<dim3(1024), dim3(256), 0, stream>>>(q, k, v, o, O1, L0, L1);
        sdpa_combine<<<dim3(4096), dim3(256), 0, stream>>>(O1, L0, L1, o);
    } else {
        sdpa_fused<<<dim3(512), dim3(256), 0, stream>>>(q, k, v, o);
    }
}

// Round 14
// 38.274 us; speedup vs baseline: 1.3045x; 1.3045x over previous
//
#include <hip/hip_runtime.h>
#include <hip/hip_bf16.h>

#define L_SEQ 1024
#define NT 32          // number of 32-row KV tiles

typedef __attribute__((ext_vector_type(8))) __bf16 bf16x8;
typedef __attribute__((ext_vector_type(4))) __bf16 bf16x4;
typedef __attribute__((ext_vector_type(4))) float f32x4;

__device__ __forceinline__ float fast_exp2(float x) {
#if __has_builtin(__builtin_amdgcn_exp2f)
    return __builtin_amdgcn_exp2f(x);
#else
    return exp2f(x);
#endif
}

#define MFMA16(a, b, c) __builtin_amdgcn_mfma_f32_16x16x32_bf16((a), (b), (c), 0, 0, 0)

// ---------------------------------------------------------------------------
// FUSED kernel, DE-FENCED (round 14). Identical math/layout/geometry to R12:
// 512 blocks x 4 waves, 32 q-rows/wave, reg-staged f32->bf16 LDS images,
// 2 buffers, 1 barrier/iter, no-max exp2 softmax, ones-MFMA l.
//
// Scheduling change ONLY: no manual vmcnt (register data-deps give the
// compiler precise per-use waits), no lgkmcnt between ds_reads and MFMAs
// (compiler emits fine-grained lgkmcnt(N), interleaving LDS reads with MFMA
// and exp2), no s_setprio (unmodeled side effects = scheduler fences).
// The single required ordering point -- all my LDS reads/writes retired
// before other waves touch the buffers -- is one lgkmcnt(0) immediately
// before the end-of-iteration s_barrier, where it is nearly free.
// ---------------------------------------------------------------------------
__global__ __launch_bounds__(256) void sdpa_fused(
    const float* __restrict__ Q, const float* __restrict__ K,
    const float* __restrict__ V, float* __restrict__ O)
{
    __shared__ __align__(16) char lds[2 * 8192];

    const int tid  = threadIdx.x;
    const int lane = tid & 63;
    const int wave = tid >> 6;
    const int li   = lane & 15;
    const int h    = lane >> 4;

    // XCD-chunked swizzle: 64 consecutive logical blocks per XCD.
    const int wg = blockIdx.x;
    const int lb = (wg & 7) * 64 + (wg >> 3);
    const int b  = lb >> 3;          // batch
    const int qt = lb & 7;           // 128-row q-tile
    const int q0 = qt * 128 + wave * 16 + li;   // q-block B rows are q0 + 64

    const float* Qb = Q + (size_t)b * L_SEQ * 64;
    const char*  Kb = (const char*)(K + (size_t)b * L_SEQ * 64);
    const char*  Vb = (const char*)(V + (size_t)b * L_SEQ * 64);

    // ---- staging dest offsets (tile-invariant, precomputed)
    int kd0, kd1, vd0, vd1;
    {
        int kd[2], vd[2];
        #pragma unroll
        for (int i = 0; i < 2; ++i) {
            const int qi = tid + i * 256;          // quad index 0..511
            const int r  = qi >> 4;                // kv row 0..31
            const int d4 = (qi & 15) << 2;         // d 0..60
            const int c32 = d4 >> 5, rem = d4 & 31, hf = rem >> 4, hh = (rem & 15) >> 2;
            kd[i] = r * 128 + 2 * (((c32 * 32 + hh * 8) ^ ((r & 7) * 8)) + hf * 4);
            const int vhf = r >> 4, vh = (r & 15) >> 2, vj = r & 3;
            const int col = (vh ^ ((d4 >> 2) & 3)) * 8 + vhf * 4 + vj;
            vd[i] = 4096 + d4 * 64 + 2 * col;      // +64*u for d4+u (col const)
        }
        kd0 = kd[0]; kd1 = kd[1]; vd0 = vd[0]; vd1 = vd[1];
    }

    // ---- Q fragments (both q-blocks): fold (1/temperature)*log2(e)
    const float QSC = 0.18033688011112042f;   // 0.125 * log2(e)
    bf16x8 qA0, qA1, qB0, qB1;
    {
        const float* ra = &Qb[(size_t)q0 * 64];
        const float* rb = &Qb[(size_t)(q0 + 64) * 64];
        f32x4 a00 = *(const f32x4*)&ra[0  + h * 4];
        f32x4 a01 = *(const f32x4*)&ra[16 + h * 4];
        f32x4 a10 = *(const f32x4*)&ra[32 + h * 4];
        f32x4 a11 = *(const f32x4*)&ra[48 + h * 4];
        f32x4 b00 = *(const f32x4*)&rb[0  + h * 4];
        f32x4 b01 = *(const f32x4*)&rb[16 + h * 4];
        f32x4 b10 = *(const f32x4*)&rb[32 + h * 4];
        f32x4 b11 = *(const f32x4*)&rb[48 + h * 4];
        #pragma unroll
        for (int j = 0; j < 4; ++j) {
            qA0[j]     = (__bf16)(a00[j] * QSC);
            qA0[4 + j] = (__bf16)(a01[j] * QSC);
            qA1[j]     = (__bf16)(a10[j] * QSC);
            qA1[4 + j] = (__bf16)(a11[j] * QSC);
            qB0[j]     = (__bf16)(b00[j] * QSC);
            qB0[4 + j] = (__bf16)(b01[j] * QSC);
            qB1[j]     = (__bf16)(b10[j] * QSC);
            qB1[4 + j] = (__bf16)(b11[j] * QSC);
        }
    }

    bf16x8 ones;
    #pragma unroll
    for (int j = 0; j < 8; ++j) ones[j] = (__bf16)1.0f;

    const float NBIAS = -46.0f;   // log2-domain bias, cancels in O = PV/l
    f32x4 oA0 = {0.f,0.f,0.f,0.f}, oA1 = {0.f,0.f,0.f,0.f};
    f32x4 oA2 = {0.f,0.f,0.f,0.f}, oA3 = {0.f,0.f,0.f,0.f};
    f32x4 oB0 = {0.f,0.f,0.f,0.f}, oB1 = {0.f,0.f,0.f,0.f};
    f32x4 oB2 = {0.f,0.f,0.f,0.f}, oB3 = {0.f,0.f,0.f,0.f};
    f32x4 olA = {0.f,0.f,0.f,0.f}, olB = {0.f,0.f,0.f,0.f};

    // ---- reg-staging: 4 float4 per thread per tile (K x2, V x2)
    f32x4 sk0, sk1, sv0, sv1;
    auto load = [&](int t) {
        const size_t tb = (size_t)t * 8192;
        sk0 = *(const f32x4*)(Kb + tb + (tid << 4));
        sk1 = *(const f32x4*)(Kb + tb + ((tid + 256) << 4));
        sv0 = *(const f32x4*)(Vb + tb + (tid << 4));
        sv1 = *(const f32x4*)(Vb + tb + ((tid + 256) << 4));
    };
    auto writebuf = [&](int bi) {
        char* B = lds + bi * 8192;
        bf16x4 a, c;
        #pragma unroll
        for (int j = 0; j < 4; ++j) { a[j] = (__bf16)sk0[j]; c[j] = (__bf16)sk1[j]; }
        *(bf16x4*)(B + kd0) = a;
        *(bf16x4*)(B + kd1) = c;
        #pragma unroll
        for (int u = 0; u < 4; ++u) {
            *((__bf16*)(B + vd0 + 64 * u)) = (__bf16)sv0[u];
            *((__bf16*)(B + vd1 + 64 * u)) = (__bf16)sv1[u];
        }
    };

    const int kswz = (li & 7) << 4;
    const int vswz = ((li >> 2) & 3) << 4;   // matches (d>>2)&3 write swizzle

    auto body = [&](int bi) {
        const char* bb = lds + bi * 8192;
        // K fragments (swizzled image; shared by both q-blocks)
        bf16x8 kf00 = *(const bf16x8*)(bb + li * 128 + ((h * 16) ^ kswz));
        bf16x8 kf01 = *(const bf16x8*)(bb + li * 128 + ((64 + h * 16) ^ kswz));
        bf16x8 kf10 = *(const bf16x8*)(bb + 2048 + li * 128 + ((h * 16) ^ kswz));
        bf16x8 kf11 = *(const bf16x8*)(bb + 2048 + li * 128 + ((64 + h * 16) ^ kswz));
        // V^T fragments (chunk-swizzled image; shared)
        const char* vb = bb + 4096;
        bf16x8 vf0 = *(const bf16x8*)(vb + (0 * 16 + li) * 64 + ((h * 16) ^ vswz));
        bf16x8 vf1 = *(const bf16x8*)(vb + (1 * 16 + li) * 64 + ((h * 16) ^ vswz));
        bf16x8 vf2 = *(const bf16x8*)(vb + (2 * 16 + li) * 64 + ((h * 16) ^ vswz));
        bf16x8 vf3 = *(const bf16x8*)(vb + (3 * 16 + li) * 64 + ((h * 16) ^ vswz));
        // NO manual lgkmcnt here: compiler emits fine-grained lgkmcnt(N) per
        // MFMA operand, so LDS reads overlap MFMA issue and exp2 VALU.

        // ---- QK^T for both q-blocks (bias pre-loaded in accumulator)
        const f32x4 nb = {NBIAS, NBIAS, NBIAS, NBIAS};
        f32x4 sA0 = MFMA16(kf01, qA1, MFMA16(kf00, qA0, nb));
        f32x4 sA1 = MFMA16(kf11, qA1, MFMA16(kf10, qA0, nb));
        f32x4 sB0 = MFMA16(kf01, qB1, MFMA16(kf00, qB0, nb));
        f32x4 sB1 = MFMA16(kf11, qB1, MFMA16(kf10, qB0, nb));

        // ---- exponentiate (no max, no cross-lane): p = 2^(s - 46)
        bf16x8 pfA, pfB;
        #pragma unroll
        for (int r = 0; r < 4; ++r) {
            pfA[r]     = (__bf16)fast_exp2(sA0[r]);
            pfA[4 + r] = (__bf16)fast_exp2(sA1[r]);
            pfB[r]     = (__bf16)fast_exp2(sB0[r]);
            pfB[4 + r] = (__bf16)fast_exp2(sB1[r]);
        }

        // ---- PV for both q-blocks + l via ones-MFMA
        oA0 = MFMA16(vf0, pfA, oA0);
        oA1 = MFMA16(vf1, pfA, oA1);
        oA2 = MFMA16(vf2, pfA, oA2);
        oA3 = MFMA16(vf3, pfA, oA3);
        olA = MFMA16(ones, pfA, olA);
        oB0 = MFMA16(vf0, pfB, oB0);
        oB1 = MFMA16(vf1, pfB, oB1);
        oB2 = MFMA16(vf2, pfB, oB2);
        oB3 = MFMA16(vf3, pfB, oB3);
        olB = MFMA16(ones, pfB, olB);
    };

    // end-of-iteration ordering point: all of this wave's LDS reads/writes
    // retired before any wave crosses into the next iteration's buffer reuse.
    auto fence_barrier = [&]() {
        asm volatile("s_waitcnt lgkmcnt(0)" ::: "memory");
        __builtin_amdgcn_s_barrier();
    };

    // ---- prologue: tile 0 staged, tile 1 loads in flight
    load(0);
    writebuf(0);               // cvt data-deps force precise vmcnt waits
    load(1);
    fence_barrier();

    #pragma unroll 2
    for (int t = 0; t < NT - 2; ++t) {
        writebuf((t + 1) & 1);   // write tile t+1 (regs; auto vmcnt waits)
        load(t + 2);             // issue tile t+2 loads
        body(t & 1);             // compute tile t (reads interleave w/ MFMA)
        fence_barrier();
    }
    // t = 30: write tile 31, no more loads
    writebuf(31 & 1);
    body(30 & 1);
    fence_barrier();
    // t = 31
    body(31 & 1);

    // ---- finalize: l replicated in ol*[r] (ones-MFMA)
    const float ilA = 1.f / olA[0];
    const float ilB = 1.f / olB[0];

    float* ObA = O + ((size_t)b * L_SEQ + q0) * 64;
    float* ObB = ObA + 64 * 64;
    f32x4 ov;
    #pragma unroll
    for (int r = 0; r < 4; ++r) ov[r] = oA0[r] * ilA;
    *(f32x4*)&ObA[0 * 16 + h * 4] = ov;
    #pragma unroll
    for (int r = 0; r < 4; ++r) ov[r] = oA1[r] * ilA;
    *(f32x4*)&ObA[1 * 16 + h * 4] = ov;
    #pragma unroll
    for (int r = 0; r < 4; ++r) ov[r] = oA2[r] * ilA;
    *(f32x4*)&ObA[2 * 16 + h * 4] = ov;
    #pragma unroll
    for (int r = 0; r < 4; ++r) ov[r] = oA3[r] * ilA;
    *(f32x4*)&ObA[3 * 16 + h * 4] = ov;
    #pragma unroll
    for (int r = 0; r < 4; ++r) ov[r] = oB0[r] * ilB;
    *(f32x4*)&ObB[0 * 16 + h * 4] = ov;
    #pragma unroll
    for (int r = 0; r < 4; ++r) ov[r] = oB1[r] * ilB;
    *(f32x4*)&ObB[1 * 16 + h * 4] = ov;
    #pragma unroll
    for (int r = 0; r < 4; ++r) ov[r] = oB2[r] * ilB;
    *(f32x4*)&ObB[2 * 16 + h * 4] = ov;
    #pragma unroll
    for (int r = 0; r < 4; ++r) ov[r] = oB3[r] * ilB;
    *(f32x4*)&ObB[3 * 16 + h * 4] = ov;
}

extern "C" void kernel_launch(void* const* d_in, const int* in_sizes, int n_in,
                              void* d_out, int out_size, void* d_ws, size_t ws_size,
                              hipStream_t stream) {
    const float* q = (const float*)d_in[0];
    const float* k = (const float*)d_in[1];
    const float* v = (const float*)d_in[2];
    float* o = (float*)d_out;

    sdpa_fused<<<dim3(512), dim3(256), 0, stream>>>(q, k, v, o);
}